// Round 1
// baseline (75.600 us; speedup 1.0000x reference)
//
#include <hip/hip_runtime.h>

// And_Convolution: out[n,w] = min_{j=0..15}( input[n, 4*w + j] * weight[j] )
// N=1024, L=8192, KERNEL=16, STRIDE=4 -> NWIN = 2045.
//
// v2: one block per row. Stage the full 32 KB row in LDS with perfectly
// coalesced float4 loads (each chunk fetched from global EXACTLY once,
// 1 KB per wave-instruction), then compute windows from LDS.
//   - VMEM instrs per output: 8 loads / 8 windows per thread = 1 (was 4)
//   - LDS reads: consecutive-lane ds_read_b128 -> canonical conflict-free
//   - grid = 1024 blocks = 4 blocks/CU (32 KB LDS each, 128/160 KB)
// HBM floor: 32 MiB read + 8.4 MB write ~= 6.5 us @ 6.2 TB/s.

#define KER 16
#define STR 4
#define ROWLEN 8192
#define NCHUNK (ROWLEN / 4)   // 2048 float4 chunks per row
#define NWIN 2045             // (ROWLEN - KER) / STR + 1
#define BLOCK 256
#define PER_T (NCHUNK / BLOCK) // 8 chunks (and 8 windows) per thread

__global__ __launch_bounds__(BLOCK) void and_conv_kernel(
    const float* __restrict__ inp,
    const float* __restrict__ wgt,
    float* __restrict__ out) {
    __shared__ float4 srow[NCHUNK];  // 32 KB: the whole input row

    const int t = threadIdx.x;
    const int n = blockIdx.x;

    const float4* __restrict__ row = (const float4*)(inp + (size_t)n * ROWLEN);

    // Stage row -> LDS. Lane t, pass j loads chunk t + 256*j: consecutive
    // lanes hit consecutive 16B -> fully coalesced, each byte loaded once.
#pragma unroll
    for (int j = 0; j < PER_T; ++j) {
        const int c = t + BLOCK * j;
        srow[c] = row[c];
    }

    // Weights: wave-uniform address -> scalar loads; overlap with staging.
    const float4* wv = (const float4*)wgt;
    const float4 w0 = wv[0];
    const float4 w1 = wv[1];
    const float4 w2 = wv[2];
    const float4 w3 = wv[3];

    __syncthreads();

    float* __restrict__ orow = out + (size_t)n * NWIN;

    // Thread t computes windows t + 256*j. Window w needs chunks w..w+3.
    // LDS reads: consecutive lanes read consecutive float4 -> conflict-free.
#pragma unroll
    for (int j = 0; j < PER_T; ++j) {
        const int w = t + BLOCK * j;
        if (w < NWIN) {  // only j==7, t>=253 masked out
            const float4 c0 = srow[w];
            const float4 c1 = srow[w + 1];
            const float4 c2 = srow[w + 2];
            const float4 c3 = srow[w + 3];

            const float m0 = fminf(fminf(c0.x * w0.x, c0.y * w0.y),
                                   fminf(c0.z * w0.z, c0.w * w0.w));
            const float m1 = fminf(fminf(c1.x * w1.x, c1.y * w1.y),
                                   fminf(c1.z * w1.z, c1.w * w1.w));
            const float m2 = fminf(fminf(c2.x * w2.x, c2.y * w2.y),
                                   fminf(c2.z * w2.z, c2.w * w2.w));
            const float m3 = fminf(fminf(c3.x * w3.x, c3.y * w3.y),
                                   fminf(c3.z * w3.z, c3.w * w3.w));

            orow[w] = fminf(fminf(m0, m1), fminf(m2, m3));
        }
    }
}

extern "C" void kernel_launch(void* const* d_in, const int* in_sizes, int n_in,
                              void* d_out, int out_size, void* d_ws, size_t ws_size,
                              hipStream_t stream) {
    const float* inp = (const float*)d_in[0];
    const float* wgt = (const float*)d_in[1];
    float* out = (float*)d_out;

    const int N = in_sizes[0] / ROWLEN;  // 1024 rows, one block each
    and_conv_kernel<<<dim3(N), dim3(BLOCK), 0, stream>>>(inp, wgt, out);
}